// Round 13
// baseline (317.830 us; speedup 1.0000x reference)
//
#include <hip/hip_runtime.h>
#include <hip/hip_bf16.h>

#define NB    1024          // B
#define NRG   16            // NREG
#define NC    128           // C
#define NH    256           // H
#define NNODE (NB*NRG)      // 16384
#define NEDGE 131072        // E
#define NEP   256           // NE = NREG^2

typedef __attribute__((ext_vector_type(8))) short short8;
typedef __attribute__((ext_vector_type(4))) float f32x4;

__device__ __forceinline__ unsigned short f2bf(float f) {
    union { float f; unsigned int u; } x; x.f = f;
    unsigned int u = x.u + 0x7fffu + ((x.u >> 16) & 1u);   // RNE
    return (unsigned short)(u >> 16);
}

// ------- mega prep kernel: state cast + WcT + W1T + W2T + deg atomics -------
// blocks [0,8192): stateB; [8192,8256): WcT; [8256,8512): W1T;
// [8512,8768): W2T; [8768,9280): deg (atomic histogram of edge dst)
__global__ void prep_kernel(const float* __restrict__ state, unsigned short* __restrict__ stateB,
                            const float* __restrict__ Wc, unsigned short* __restrict__ WcT,
                            const float* __restrict__ W1, unsigned short* __restrict__ W1T,
                            const float* __restrict__ W2, unsigned short* __restrict__ W2T,
                            const int* __restrict__ ei, int* __restrict__ deg) {
    int b = blockIdx.x, t = threadIdx.x;
    if (b < 8192) { int i = b * 256 + t; stateB[i] = f2bf(state[i]); return; }
    b -= 8192;
    if (b < 64) {   // WcT[c*128+r] = Wc[r*128+c], contiguous writes
        int i = b * 256 + t; int r = i & 127, c = i >> 7;
        WcT[c * 128 + r] = f2bf(Wc[r * 128 + c]); return;
    }
    b -= 64;
    if (b < 256) {  // W1T[j*128+k]: j<256 -> W1a, else W1b
        int i = b * 256 + t; int k = i & 127, j = i >> 7;
        float v = (j < NH) ? W1[k * NH + j] : W1[(128 + k) * NH + (j - NH)];
        W1T[j * 128 + k] = f2bf(v); return;
    }
    b -= 256;
    if (b < 256) {  // W2T[c*256+r] = W2[r*256+c], contiguous writes
        int i = b * 256 + t; int r = i & 255, c = i >> 8;
        W2T[c * 256 + r] = f2bf(W2[r * 256 + c]); return;
    }
    b -= 256;
    {   // degree histogram (memset of deg precedes this kernel in-stream)
        int e = b * 256 + t;
        if (e < NEDGE) atomicAdd(&deg[ei[NEDGE + e] & (NNODE - 1)], 1);
    }
}

// ---------------- GCN: CSR build ----------------

// wave-shfl scan + one atomic per wave
__global__ void offs_kernel(const int* __restrict__ deg, int* __restrict__ off,
                            float* __restrict__ dinv, int* __restrict__ gctr) {
    int n = blockIdx.x * 256 + threadIdx.x;
    int lane = threadIdx.x & 63;
    int d = deg[n];
    int s = d;                               // inclusive wave scan
    #pragma unroll
    for (int o = 1; o < 64; o <<= 1) {
        int u = __shfl_up(s, o, 64);
        if (lane >= o) s += u;
    }
    int base = 0;
    if (lane == 63) base = atomicAdd(gctr, s);
    base = __shfl(base, 63, 64);
    off[n] = base + s - d;
    dinv[n] = rsqrtf((float)(d + 1));        // +1 self-loop
}

__global__ void scatter_kernel(const int* __restrict__ ei, const int* __restrict__ off,
                               int* __restrict__ cursor, int* __restrict__ csr) {
    int e = blockIdx.x * 256 + threadIdx.x;
    if (e < NEDGE) {
        int d = ei[NEDGE + e] & (NNODE - 1);
        int p = atomicAdd(&cursor[d], 1);
        csr[off[d] + p] = ei[e] & (NNODE - 1);
    }
}

// y rows already scaled by dinv (folded into GEMM1 epilogue):
// x = relu(dinv[n]*(y[n] + sum y[src]) + bc) + state, emit bf16
// v5: neighbor indices LDS-staged (1 coalesced load per 32 nbrs, then ILP on rows)
__global__ __launch_bounds__(128) void gather_kernel(
    const float* __restrict__ y, const int* __restrict__ csr,
    const int* __restrict__ off, const int* __restrict__ deg,
    const float* __restrict__ dinv, const float* __restrict__ bc,
    const float* __restrict__ state, unsigned short* __restrict__ xb) {
    __shared__ int nb[32];
    int n = blockIdx.x, ch = threadIdx.x;
    int st = off[n], d = deg[n];
    float acc = y[(size_t)n * NC + ch];            // self loop
    for (int base = 0; base < d; base += 32) {     // d uniform per block -> safe syncs
        int cnt = min(d - base, 32);
        if (ch < cnt) nb[ch] = csr[st + base + ch];
        __syncthreads();
        #pragma unroll 4
        for (int i = 0; i < cnt; i++)
            acc += y[(size_t)nb[i] * NC + ch];
        __syncthreads();
    }
    acc *= dinv[n];
    float o = fmaxf(acc + bc[ch], 0.f) + state[(size_t)n * NC + ch];
    xb[(size_t)n * NC + ch] = f2bf(o);
}

// ---------------- bf16 MFMA GEMM, K=128, tile 64x64, 256 thr ----------------
// A [M][128] bf16 row-major, BT [N][128] bf16 row-major. D [M][N] fp32.
// optional bias on cols < biasLim; optional per-row scale (dinv for GEMM1).
__global__ __launch_bounds__(256) void gemm_bf16_k128(
    const unsigned short* __restrict__ A, const unsigned short* __restrict__ BT,
    float* __restrict__ D, int N, const float* __restrict__ bias, int biasLim,
    const float* __restrict__ rowscale) {
    __shared__ unsigned short As[64 * 128];
    __shared__ unsigned short Bs[64 * 128];
    const int m0 = blockIdx.x << 6, n0 = blockIdx.y << 6;
    const int t = threadIdx.x, lane = t & 63, w = t >> 6;
    {
        const int r = t >> 2, seg = t & 3;
        const uint4* ga = (const uint4*)(A + ((size_t)(m0 + r) << 7) + (seg << 5));
        const uint4* gb = (const uint4*)(BT + ((size_t)(n0 + r) << 7) + (seg << 5));
        uint4 a0 = ga[0], a1 = ga[1], a2 = ga[2], a3 = ga[3];
        uint4 c0 = gb[0], c1 = gb[1], c2 = gb[2], c3 = gb[3];
        char* ap = (char*)As + r * 256;
        char* bp = (char*)Bs + r * 256;
        int cb = seg << 6, sw = (r & 7) << 4;
        *(uint4*)(ap + ((cb +  0) ^ sw)) = a0;
        *(uint4*)(ap + ((cb + 16) ^ sw)) = a1;
        *(uint4*)(ap + ((cb + 32) ^ sw)) = a2;
        *(uint4*)(ap + ((cb + 48) ^ sw)) = a3;
        *(uint4*)(bp + ((cb +  0) ^ sw)) = c0;
        *(uint4*)(bp + ((cb + 16) ^ sw)) = c1;
        *(uint4*)(bp + ((cb + 32) ^ sw)) = c2;
        *(uint4*)(bp + ((cb + 48) ^ sw)) = c3;
    }
    __syncthreads();
    f32x4 acc[4];
    #pragma unroll
    for (int n = 0; n < 4; n++) acc[n] = (f32x4){0.f, 0.f, 0.f, 0.f};
    const int arow = (w << 4) + (lane & 15);
    const int asw = (arow & 7) << 4;
    #pragma unroll
    for (int s = 0; s < 4; s++) {
        short8 af = *(const short8*)((const char*)As + arow * 256 +
                                     (((s << 6) + ((lane >> 4) << 4)) ^ asw));
        #pragma unroll
        for (int n = 0; n < 4; n++) {
            int brow = (n << 4) + (lane & 15);
            short8 bf = *(const short8*)((const char*)Bs + brow * 256 +
                         (((s << 6) + ((lane >> 4) << 4)) ^ ((brow & 7) << 4)));
            acc[n] = __builtin_amdgcn_mfma_f32_16x16x32_bf16(af, bf, acc[n], 0, 0, 0);
        }
    }
    const int rb = m0 + (w << 4) + ((lane >> 4) << 2);
    float sc[4];
    #pragma unroll
    for (int r = 0; r < 4; r++) sc[r] = rowscale ? rowscale[rb + r] : 1.f;
    #pragma unroll
    for (int n = 0; n < 4; n++) {
        int col = n0 + (n << 4) + (lane & 15);
        float bv = 0.f;
        if (bias != nullptr && col < biasLim) bv = bias[col];
        #pragma unroll
        for (int r = 0; r < 4; r++)
            D[(size_t)(rb + r) * N + col] = acc[n][r] * sc[r] + bv;   // m89 C/D mapping
    }
}

// ---------------- fused per-batch critic kernel (v4: occupancy-tuned) ----------------
// acc[4][2] (wave = 64e x 32h, two n-half passes) -> VGPR <= 128 -> 4 waves/SIMD.
__global__ __launch_bounds__(256, 4) void fused_kernel(
    const float* __restrict__ UV, const unsigned short* __restrict__ W2T,
    const int* __restrict__ edges, const float* __restrict__ action,
    const float* __restrict__ W1, const float* __restrict__ b2,
    const float* __restrict__ W3, const float* __restrict__ b3,
    float* __restrict__ out) {
    __shared__ unsigned short h1s[64 * 256];           // 32 KB, XOR-swizzled rows
    __shared__ int srcL[NEP], dstL[NEP];
    __shared__ float aL[NEP], w1cL[NH], b2L[NH], w3L[NH];
    __shared__ float red[4];
    const int b = blockIdx.x;
    const int t = threadIdx.x;
    const int lane = t & 63;
    const int w = t >> 6;
    srcL[t] = edges[2 * t] & (NRG - 1);
    dstL[t] = edges[2 * t + 1] & (NRG - 1);
    aL[t]   = action[(size_t)b * NEP + t];
    w1cL[t] = W1[256 * NH + t];
    b2L[t]  = b2[t];
    w3L[t]  = W3[t];
    __syncthreads();

    const int kO = t & 31;     // k-octet (8 floats)
    const int eS = t >> 5;     // e sub-row 0..7
    const float4 wc0 = *(const float4*)(w1cL + (kO << 3));       // hoisted to regs
    const float4 wc1 = *(const float4*)(w1cL + (kO << 3) + 4);
    const float* UVb = UV + ((size_t)b * NRG << 9);
    float partial = 0.f;

    for (int c = 0; c < 4; ++c) {
        // ---- build h1 tile rows [c*64, c*64+64) ----
        #pragma unroll 4
        for (int it = 0; it < 8; ++it) {
            int el = (it << 3) + eS;
            int e  = (c << 6) + el;
            int sn = srcL[e], dn = dstL[e];
            float ae = aL[e];
            const float* up = UVb + (sn << 9) + (kO << 3);
            const float* vp = UVb + (dn << 9) + NH + (kO << 3);
            float4 u0 = *(const float4*)up;
            float4 u1 = *(const float4*)(up + 4);
            float4 v0 = *(const float4*)vp;
            float4 v1 = *(const float4*)(vp + 4);
            union { unsigned short us[8]; uint4 q; } P;
            float y;
            y = u0.x + v0.x + ae * wc0.x; P.us[0] = f2bf(fmaxf(y, 0.f));
            y = u0.y + v0.y + ae * wc0.y; P.us[1] = f2bf(fmaxf(y, 0.f));
            y = u0.z + v0.z + ae * wc0.z; P.us[2] = f2bf(fmaxf(y, 0.f));
            y = u0.w + v0.w + ae * wc0.w; P.us[3] = f2bf(fmaxf(y, 0.f));
            y = u1.x + v1.x + ae * wc1.x; P.us[4] = f2bf(fmaxf(y, 0.f));
            y = u1.y + v1.y + ae * wc1.y; P.us[5] = f2bf(fmaxf(y, 0.f));
            y = u1.z + v1.z + ae * wc1.z; P.us[6] = f2bf(fmaxf(y, 0.f));
            y = u1.w + v1.w + ae * wc1.w; P.us[7] = f2bf(fmaxf(y, 0.f));
            *(uint4*)((char*)h1s + el * 512 + ((kO << 4) ^ ((el & 7) << 4))) = P.q;
        }
        __syncthreads();
        // ---- two n-half passes: wave tile 64e x 32h, acc[4][2] ----
        #pragma unroll
        for (int nh = 0; nh < 2; ++nh) {
            f32x4 acc[4][2];
            #pragma unroll
            for (int m = 0; m < 4; m++)
                #pragma unroll
                for (int n = 0; n < 2; n++) acc[m][n] = (f32x4){0.f, 0.f, 0.f, 0.f};
            #pragma unroll
            for (int s = 0; s < 8; ++s) {
                short8 af[4];
                #pragma unroll
                for (int m = 0; m < 4; m++) {
                    int row = (m << 4) + (lane & 15);
                    af[m] = *(const short8*)((const char*)h1s + row * 512 +
                              (((s << 6) + ((lane >> 4) << 4)) ^ ((row & 7) << 4)));
                }
                #pragma unroll
                for (int n = 0; n < 2; n++) {
                    int col = (w << 6) + (nh << 5) + (n << 4) + (lane & 15);
                    short8 bf = *(const short8*)(W2T + (size_t)col * NH + (s << 5) +
                                                 ((lane >> 4) << 3));
                    #pragma unroll
                    for (int m = 0; m < 4; m++)
                        acc[m][n] = __builtin_amdgcn_mfma_f32_16x16x32_bf16(
                                        af[m], bf, acc[m][n], 0, 0, 0);
                }
            }
            // epilogue: sum over e makes C/D row-mapping irrelevant
            #pragma unroll
            for (int n = 0; n < 2; n++) {
                int col = (w << 6) + (nh << 5) + (n << 4) + (lane & 15);
                float bb = b2L[col], ww = w3L[col];
                #pragma unroll
                for (int m = 0; m < 4; m++)
                    #pragma unroll
                    for (int r = 0; r < 4; r++)
                        partial += fmaxf(acc[m][n][r] + bb, 0.f) * ww;
            }
        }
        __syncthreads();   // h1s safe to overwrite next chunk
    }
    #pragma unroll
    for (int o = 32; o; o >>= 1) partial += __shfl_down(partial, o, 64);
    if (lane == 0) red[w] = partial;
    __syncthreads();
    if (t == 0) out[b] = red[0] + red[1] + red[2] + red[3] + b3[0];
}

// ---------------- launcher ----------------
// Workspace (37.03 MB, liveness-overlapped). v6 FIX: offs/dinv moved past csr
// end (v4/v5 had offs overlapping csr's last 12288 B -> scatter clobbered offs).
// Verified disjoint [start,end) spans:
//   stateB/xB [0,        4194304)
//   y         [4194304, 12582912)   UV [4194304, 37748736) (aliases y, ordered)
//   WcT       [37748736, 37781504)
//   W1T       [37781504, 37912576)
//   W2T       [37912576, 38043648)
//   deg       [38043648, 38109184)
//   cursor    [38109184, 38174720)
//   csr       [38174720, 38699008)   gctr = csr[0] (dead before scatter writes)
//   offs      [38699008, 38764544)
//   dinv      [38764544, 38830080)
// Single memset zeroes deg+cursor+gctr (131076 B contiguous).
// 8 dispatches: memset, prep(+deg), offs, scatter, gemm1, gather, gemm2, fused.

extern "C" void kernel_launch(void* const* d_in, const int* in_sizes, int n_in,
                              void* d_out, int out_size, void* d_ws, size_t ws_size,
                              hipStream_t stream) {
    const float* state  = (const float*)d_in[0];
    const int*   ei     = (const int*)d_in[1];
    const float* action = (const float*)d_in[2];
    const int*   edges  = (const int*)d_in[3];
    const float* Wc     = (const float*)d_in[4];
    const float* bc     = (const float*)d_in[5];
    const float* W1     = (const float*)d_in[6];
    const float* b1     = (const float*)d_in[7];
    const float* W2     = (const float*)d_in[8];
    const float* b2     = (const float*)d_in[9];
    const float* W3     = (const float*)d_in[10];
    const float* b3     = (const float*)d_in[11];
    float* out = (float*)d_out;

    if (ws_size < 38830080u) return;   // diagnosable wrong-answer, not OOB crash

    char* ws = (char*)d_ws;
    unsigned short* stateB = (unsigned short*)(ws + 0);          // 4 MB
    unsigned short* xB     = (unsigned short*)(ws + 0);          // aliases stateB
    float*          y      = (float*)(ws + 4194304);             // 8 MB
    float*          UV     = (float*)(ws + 4194304);             // 32 MB, aliases y
    unsigned short* WcT    = (unsigned short*)(ws + 37748736);   // 32 KB
    unsigned short* W1T    = (unsigned short*)(ws + 37781504);   // 128 KB
    unsigned short* W2T    = (unsigned short*)(ws + 37912576);   // 128 KB
    int*            deg    = (int*)(ws + 38043648);              // 64 KB
    int*            cursor = (int*)(ws + 38109184);              // 64 KB
    int*            csr    = (int*)(ws + 38174720);              // 512 KB -> 38699008
    int*            gctr   = (int*)(ws + 38174720);              // aliases csr[0]
    int*            offs   = (int*)(ws + 38699008);              // 64 KB -> 38764544
    float*          dinv   = (float*)(ws + 38764544);            // 64 KB -> 38830080

    hipMemsetAsync(ws + 38043648, 0, 131076, stream);            // deg|cursor|gctr

    prep_kernel<<<9280, 256, 0, stream>>>(state, stateB, Wc, WcT, W1, W1T, W2, W2T,
                                          ei, deg);

    offs_kernel<<<NNODE / 256, 256, 0, stream>>>(deg, offs, dinv, gctr);
    scatter_kernel<<<NEDGE / 256, 256, 0, stream>>>(ei, offs, cursor, csr);

    // y = (state @ Wc) * dinv[row]   [16384,128]x[128,128]
    gemm_bf16_k128<<<dim3(NNODE / 64, 2), 256, 0, stream>>>(stateB, WcT, y, 128,
                                                            nullptr, 0, dinv);
    gather_kernel<<<NNODE, 128, 0, stream>>>(y, csr, offs, deg, dinv, bc, state, xB);
    // UV = x @ [W1a | W1b] (+b1 on U half)   [16384,128]x[128,512]
    gemm_bf16_k128<<<dim3(NNODE / 64, 8), 256, 0, stream>>>(xB, W1T, UV, 512, b1, NH,
                                                            nullptr);

    fused_kernel<<<NB, 256, 0, stream>>>(UV, W2T, edges, action, W1, b2, W3, b3, out);
}

// Round 14
// 216.592 us; speedup vs baseline: 1.4674x; 1.4674x over previous
//
#include <hip/hip_runtime.h>
#include <hip/hip_bf16.h>

#define NB    1024          // B
#define NRG   16            // NREG
#define NC    128           // C
#define NH    256           // H
#define NNODE (NB*NRG)      // 16384
#define NEDGE 131072        // E
#define NEP   256           // NE = NREG^2

typedef __attribute__((ext_vector_type(8))) short short8;
typedef __attribute__((ext_vector_type(4))) float f32x4;

__device__ __forceinline__ unsigned short f2bf(float f) {
    union { float f; unsigned int u; } x; x.f = f;
    unsigned int u = x.u + 0x7fffu + ((x.u >> 16) & 1u);   // RNE
    return (unsigned short)(u >> 16);
}

// ------- mega prep kernel: state cast + WcT + W1T + W2T + deg atomics -------
// blocks [0,8192): stateB; [8192,8256): WcT; [8256,8512): W1T;
// [8512,8768): W2T; [8768,9280): deg (atomic histogram of edge dst)
__global__ void prep_kernel(const float* __restrict__ state, unsigned short* __restrict__ stateB,
                            const float* __restrict__ Wc, unsigned short* __restrict__ WcT,
                            const float* __restrict__ W1, unsigned short* __restrict__ W1T,
                            const float* __restrict__ W2, unsigned short* __restrict__ W2T,
                            const int* __restrict__ ei, int* __restrict__ deg) {
    int b = blockIdx.x, t = threadIdx.x;
    if (b < 8192) { int i = b * 256 + t; stateB[i] = f2bf(state[i]); return; }
    b -= 8192;
    if (b < 64) {   // WcT[c*128+r] = Wc[r*128+c], contiguous writes
        int i = b * 256 + t; int r = i & 127, c = i >> 7;
        WcT[c * 128 + r] = f2bf(Wc[r * 128 + c]); return;
    }
    b -= 64;
    if (b < 256) {  // W1T[j*128+k]: j<256 -> W1a, else W1b
        int i = b * 256 + t; int k = i & 127, j = i >> 7;
        float v = (j < NH) ? W1[k * NH + j] : W1[(128 + k) * NH + (j - NH)];
        W1T[j * 128 + k] = f2bf(v); return;
    }
    b -= 256;
    if (b < 256) {  // W2T[c*256+r] = W2[r*256+c], contiguous writes
        int i = b * 256 + t; int r = i & 255, c = i >> 8;
        W2T[c * 256 + r] = f2bf(W2[r * 256 + c]); return;
    }
    b -= 256;
    {   // degree histogram (memset of deg precedes this kernel in-stream)
        int e = b * 256 + t;
        if (e < NEDGE) atomicAdd(&deg[ei[NEDGE + e] & (NNODE - 1)], 1);
    }
}

// ---------------- GCN: CSR build ----------------

// wave-shfl scan + one atomic per wave
__global__ void offs_kernel(const int* __restrict__ deg, int* __restrict__ off,
                            float* __restrict__ dinv, int* __restrict__ gctr) {
    int n = blockIdx.x * 256 + threadIdx.x;
    int lane = threadIdx.x & 63;
    int d = deg[n];
    int s = d;                               // inclusive wave scan
    #pragma unroll
    for (int o = 1; o < 64; o <<= 1) {
        int u = __shfl_up(s, o, 64);
        if (lane >= o) s += u;
    }
    int base = 0;
    if (lane == 63) base = atomicAdd(gctr, s);
    base = __shfl(base, 63, 64);
    off[n] = base + s - d;
    dinv[n] = rsqrtf((float)(d + 1));        // +1 self-loop
}

__global__ void scatter_kernel(const int* __restrict__ ei, const int* __restrict__ off,
                               int* __restrict__ cursor, int* __restrict__ csr) {
    int e = blockIdx.x * 256 + threadIdx.x;
    if (e < NEDGE) {
        int d = ei[NEDGE + e] & (NNODE - 1);
        int p = atomicAdd(&cursor[d], 1);
        csr[off[d] + p] = ei[e] & (NNODE - 1);
    }
}

// y rows already scaled by dinv (folded into GEMM1 epilogue):
// x = relu(dinv[n]*(y[n] + sum y[src]) + bc) + state, emit bf16
// neighbor indices LDS-staged (1 coalesced load per 32 nbrs, then ILP on rows)
__global__ __launch_bounds__(128) void gather_kernel(
    const float* __restrict__ y, const int* __restrict__ csr,
    const int* __restrict__ off, const int* __restrict__ deg,
    const float* __restrict__ dinv, const float* __restrict__ bc,
    const float* __restrict__ state, unsigned short* __restrict__ xb) {
    __shared__ int nb[32];
    int n = blockIdx.x, ch = threadIdx.x;
    int st = off[n], d = deg[n];
    float acc = y[(size_t)n * NC + ch];            // self loop
    for (int base = 0; base < d; base += 32) {     // d uniform per block -> safe syncs
        int cnt = min(d - base, 32);
        if (ch < cnt) nb[ch] = csr[st + base + ch];
        __syncthreads();
        #pragma unroll 4
        for (int i = 0; i < cnt; i++)
            acc += y[(size_t)nb[i] * NC + ch];
        __syncthreads();
    }
    acc *= dinv[n];
    float o = fmaxf(acc + bc[ch], 0.f) + state[(size_t)n * NC + ch];
    xb[(size_t)n * NC + ch] = f2bf(o);
}

// ---------------- bf16 MFMA GEMM, K=128, tile 64x64, 256 thr ----------------
// A [M][128] bf16 row-major, BT [N][128] bf16 row-major. D [M][N] fp32.
// optional bias on cols < biasLim; optional per-row scale (dinv for GEMM1).
__global__ __launch_bounds__(256) void gemm_bf16_k128(
    const unsigned short* __restrict__ A, const unsigned short* __restrict__ BT,
    float* __restrict__ D, int N, const float* __restrict__ bias, int biasLim,
    const float* __restrict__ rowscale) {
    __shared__ unsigned short As[64 * 128];
    __shared__ unsigned short Bs[64 * 128];
    const int m0 = blockIdx.x << 6, n0 = blockIdx.y << 6;
    const int t = threadIdx.x, lane = t & 63, w = t >> 6;
    {
        const int r = t >> 2, seg = t & 3;
        const uint4* ga = (const uint4*)(A + ((size_t)(m0 + r) << 7) + (seg << 5));
        const uint4* gb = (const uint4*)(BT + ((size_t)(n0 + r) << 7) + (seg << 5));
        uint4 a0 = ga[0], a1 = ga[1], a2 = ga[2], a3 = ga[3];
        uint4 c0 = gb[0], c1 = gb[1], c2 = gb[2], c3 = gb[3];
        char* ap = (char*)As + r * 256;
        char* bp = (char*)Bs + r * 256;
        int cb = seg << 6, sw = (r & 7) << 4;
        *(uint4*)(ap + ((cb +  0) ^ sw)) = a0;
        *(uint4*)(ap + ((cb + 16) ^ sw)) = a1;
        *(uint4*)(ap + ((cb + 32) ^ sw)) = a2;
        *(uint4*)(ap + ((cb + 48) ^ sw)) = a3;
        *(uint4*)(bp + ((cb +  0) ^ sw)) = c0;
        *(uint4*)(bp + ((cb + 16) ^ sw)) = c1;
        *(uint4*)(bp + ((cb + 32) ^ sw)) = c2;
        *(uint4*)(bp + ((cb + 48) ^ sw)) = c3;
    }
    __syncthreads();
    f32x4 acc[4];
    #pragma unroll
    for (int n = 0; n < 4; n++) acc[n] = (f32x4){0.f, 0.f, 0.f, 0.f};
    const int arow = (w << 4) + (lane & 15);
    const int asw = (arow & 7) << 4;
    #pragma unroll
    for (int s = 0; s < 4; s++) {
        short8 af = *(const short8*)((const char*)As + arow * 256 +
                                     (((s << 6) + ((lane >> 4) << 4)) ^ asw));
        #pragma unroll
        for (int n = 0; n < 4; n++) {
            int brow = (n << 4) + (lane & 15);
            short8 bf = *(const short8*)((const char*)Bs + brow * 256 +
                         (((s << 6) + ((lane >> 4) << 4)) ^ ((brow & 7) << 4)));
            acc[n] = __builtin_amdgcn_mfma_f32_16x16x32_bf16(af, bf, acc[n], 0, 0, 0);
        }
    }
    const int rb = m0 + (w << 4) + ((lane >> 4) << 2);
    float sc[4];
    #pragma unroll
    for (int r = 0; r < 4; r++) sc[r] = rowscale ? rowscale[rb + r] : 1.f;
    #pragma unroll
    for (int n = 0; n < 4; n++) {
        int col = n0 + (n << 4) + (lane & 15);
        float bv = 0.f;
        if (bias != nullptr && col < biasLim) bv = bias[col];
        #pragma unroll
        for (int r = 0; r < 4; r++)
            D[(size_t)(rb + r) * N + col] = acc[n][r] * sc[r] + bv;   // m89 C/D mapping
    }
}

// -------- fused per-batch critic kernel (v7 = round-3 measured config) --------
// acc[4][4], plain __launch_bounds__(256): measured VGPR=176, 84.4 us, no spill.
// LESSON (v6): __launch_bounds__(256,4) + acc[4][2] forced VGPR=64 -> ~640 MB/dispatch
// scratch spill -> 197 us spill-bound. Never coerce occupancy via launch bounds here.
__global__ __launch_bounds__(256) void fused_kernel(
    const float* __restrict__ UV, const unsigned short* __restrict__ W2T,
    const int* __restrict__ edges, const float* __restrict__ action,
    const float* __restrict__ W1, const float* __restrict__ b2,
    const float* __restrict__ W3, const float* __restrict__ b3,
    float* __restrict__ out) {
    __shared__ unsigned short h1s[64 * 256];           // 32 KB, XOR-swizzled rows
    __shared__ int srcL[NEP], dstL[NEP];
    __shared__ float aL[NEP], w1cL[NH], b2L[NH], w3L[NH];
    __shared__ float red[4];
    const int b = blockIdx.x;
    const int t = threadIdx.x;
    const int lane = t & 63;
    const int w = t >> 6;
    srcL[t] = edges[2 * t] & (NRG - 1);
    dstL[t] = edges[2 * t + 1] & (NRG - 1);
    aL[t]   = action[(size_t)b * NEP + t];
    w1cL[t] = W1[256 * NH + t];
    b2L[t]  = b2[t];
    w3L[t]  = W3[t];
    __syncthreads();

    const int kO = t & 31;     // k-octet (8 floats)
    const int eS = t >> 5;     // e sub-row 0..7
    float partial = 0.f;

    for (int c = 0; c < 4; ++c) {
        // ---- build h1 tile rows [c*64, c*64+64) ----
        #pragma unroll
        for (int it = 0; it < 8; ++it) {
            int el = (it << 3) + eS;
            int e  = (c << 6) + el;
            int sn = srcL[e], dn = dstL[e];
            float ae = aL[e];
            const float* up = UV + (((size_t)b * NRG + sn) << 9) + (kO << 3);
            const float* vp = UV + (((size_t)b * NRG + dn) << 9) + NH + (kO << 3);
            float4 u0 = *(const float4*)up;
            float4 u1 = *(const float4*)(up + 4);
            float4 v0 = *(const float4*)vp;
            float4 v1 = *(const float4*)(vp + 4);
            float4 c0 = *(const float4*)(w1cL + (kO << 3));
            float4 c1 = *(const float4*)(w1cL + (kO << 3) + 4);
            union { unsigned short us[8]; uint4 q; } P;
            float y;
            y = u0.x + v0.x + ae * c0.x; P.us[0] = f2bf(y > 0.f ? y : 0.f);
            y = u0.y + v0.y + ae * c0.y; P.us[1] = f2bf(y > 0.f ? y : 0.f);
            y = u0.z + v0.z + ae * c0.z; P.us[2] = f2bf(y > 0.f ? y : 0.f);
            y = u0.w + v0.w + ae * c0.w; P.us[3] = f2bf(y > 0.f ? y : 0.f);
            y = u1.x + v1.x + ae * c1.x; P.us[4] = f2bf(y > 0.f ? y : 0.f);
            y = u1.y + v1.y + ae * c1.y; P.us[5] = f2bf(y > 0.f ? y : 0.f);
            y = u1.z + v1.z + ae * c1.z; P.us[6] = f2bf(y > 0.f ? y : 0.f);
            y = u1.w + v1.w + ae * c1.w; P.us[7] = f2bf(y > 0.f ? y : 0.f);
            *(uint4*)((char*)h1s + el * 512 + ((kO << 4) ^ ((el & 7) << 4))) = P.q;
        }
        __syncthreads();
        // ---- [64e x 64h] per wave, K=256 ----
        f32x4 acc[4][4];
        #pragma unroll
        for (int m = 0; m < 4; m++)
            #pragma unroll
            for (int n = 0; n < 4; n++) acc[m][n] = (f32x4){0.f, 0.f, 0.f, 0.f};
        for (int s = 0; s < 8; ++s) {
            short8 af[4], bf[4];
            #pragma unroll
            for (int m = 0; m < 4; m++) {
                int row = (m << 4) + (lane & 15);
                af[m] = *(const short8*)((const char*)h1s + row * 512 +
                          (((s << 6) + ((lane >> 4) << 4)) ^ ((row & 7) << 4)));
            }
            #pragma unroll
            for (int n = 0; n < 4; n++) {
                int col = (w << 6) + (n << 4) + (lane & 15);
                bf[n] = *(const short8*)(W2T + (size_t)col * NH + (s << 5) +
                                         ((lane >> 4) << 3));
            }
            #pragma unroll
            for (int m = 0; m < 4; m++)
                #pragma unroll
                for (int n = 0; n < 4; n++)
                    acc[m][n] = __builtin_amdgcn_mfma_f32_16x16x32_bf16(
                                    af[m], bf[n], acc[m][n], 0, 0, 0);
        }
        // ---- epilogue: sum over e makes C/D row-mapping irrelevant ----
        #pragma unroll
        for (int n = 0; n < 4; n++) {
            int col = (w << 6) + (n << 4) + (lane & 15);
            float bb = b2L[col], ww = w3L[col];
            #pragma unroll
            for (int m = 0; m < 4; m++)
                #pragma unroll
                for (int r = 0; r < 4; r++) {
                    float v = acc[m][n][r] + bb;
                    partial += (v > 0.f ? v : 0.f) * ww;
                }
        }
        __syncthreads();   // h1s safe to overwrite next chunk
    }
    #pragma unroll
    for (int o = 32; o; o >>= 1) partial += __shfl_down(partial, o, 64);
    if (lane == 0) red[w] = partial;
    __syncthreads();
    if (t == 0) out[b] = red[0] + red[1] + red[2] + red[3] + b3[0];
}

// ---------------- launcher ----------------
// Workspace (37.03 MB, liveness-overlapped). Verified disjoint [start,end):
//   stateB/xB [0,        4194304)
//   y         [4194304, 12582912)   UV [4194304, 37748736) (aliases y, ordered)
//   WcT       [37748736, 37781504)
//   W1T       [37781504, 37912576)
//   W2T       [37912576, 38043648)
//   deg       [38043648, 38109184)
//   cursor    [38109184, 38174720)
//   csr       [38174720, 38699008)   gctr = csr[0] (dead before scatter writes)
//   offs      [38699008, 38764544)
//   dinv      [38764544, 38830080)
// Single memset zeroes deg+cursor+gctr (131076 B contiguous).
// 8 dispatches: memset, prep(+deg), offs, scatter, gemm1, gather, gemm2, fused.

extern "C" void kernel_launch(void* const* d_in, const int* in_sizes, int n_in,
                              void* d_out, int out_size, void* d_ws, size_t ws_size,
                              hipStream_t stream) {
    const float* state  = (const float*)d_in[0];
    const int*   ei     = (const int*)d_in[1];
    const float* action = (const float*)d_in[2];
    const int*   edges  = (const int*)d_in[3];
    const float* Wc     = (const float*)d_in[4];
    const float* bc     = (const float*)d_in[5];
    const float* W1     = (const float*)d_in[6];
    const float* b1     = (const float*)d_in[7];
    const float* W2     = (const float*)d_in[8];
    const float* b2     = (const float*)d_in[9];
    const float* W3     = (const float*)d_in[10];
    const float* b3     = (const float*)d_in[11];
    float* out = (float*)d_out;

    if (ws_size < 38830080u) return;   // diagnosable wrong-answer, not OOB crash

    char* ws = (char*)d_ws;
    unsigned short* stateB = (unsigned short*)(ws + 0);          // 4 MB
    unsigned short* xB     = (unsigned short*)(ws + 0);          // aliases stateB
    float*          y      = (float*)(ws + 4194304);             // 8 MB
    float*          UV     = (float*)(ws + 4194304);             // 32 MB, aliases y
    unsigned short* WcT    = (unsigned short*)(ws + 37748736);   // 32 KB
    unsigned short* W1T    = (unsigned short*)(ws + 37781504);   // 128 KB
    unsigned short* W2T    = (unsigned short*)(ws + 37912576);   // 128 KB
    int*            deg    = (int*)(ws + 38043648);              // 64 KB
    int*            cursor = (int*)(ws + 38109184);              // 64 KB
    int*            csr    = (int*)(ws + 38174720);              // 512 KB -> 38699008
    int*            gctr   = (int*)(ws + 38174720);              // aliases csr[0]
    int*            offs   = (int*)(ws + 38699008);              // 64 KB -> 38764544
    float*          dinv   = (float*)(ws + 38764544);            // 64 KB -> 38830080

    hipMemsetAsync(ws + 38043648, 0, 131076, stream);            // deg|cursor|gctr

    prep_kernel<<<9280, 256, 0, stream>>>(state, stateB, Wc, WcT, W1, W1T, W2, W2T,
                                          ei, deg);

    offs_kernel<<<NNODE / 256, 256, 0, stream>>>(deg, offs, dinv, gctr);
    scatter_kernel<<<NEDGE / 256, 256, 0, stream>>>(ei, offs, cursor, csr);

    // y = (state @ Wc) * dinv[row]   [16384,128]x[128,128]
    gemm_bf16_k128<<<dim3(NNODE / 64, 2), 256, 0, stream>>>(stateB, WcT, y, 128,
                                                            nullptr, 0, dinv);
    gather_kernel<<<NNODE, 128, 0, stream>>>(y, csr, offs, deg, dinv, bc, state, xB);
    // UV = x @ [W1a | W1b] (+b1 on U half)   [16384,128]x[128,512]
    gemm_bf16_k128<<<dim3(NNODE / 64, 8), 256, 0, stream>>>(xB, W1T, UV, 512, b1, NH,
                                                            nullptr);

    fused_kernel<<<NB, 256, 0, stream>>>(UV, W2T, edges, action, W1, b2, W3, b3, out);
}